// Round 6
// baseline (111.418 us; speedup 1.0000x reference)
//
#include <hip/hip_runtime.h>
#include <math.h>

#define NB 32
#define KK 2
#define PP 256
#define NCLOUD 8192
#define NNODES 512   // K*P
#define NCOEF 163840 // B*K*P*COEF_D
#define SURF0 193
#define NCHUNK 16                 // chunks per batch (512 pts each)
#define NSURF (NB * NCHUNK)       // 512
#define NBLK (SURF0 + NSURF)      // 705

__device__ inline float waveSum(float v) {
#pragma unroll
  for (int o = 32; o > 0; o >>= 1) v += __shfl_down(v, o);
  return v;
}
__device__ inline float waveMax(float v) {
#pragma unroll
  for (int o = 32; o > 0; o >>= 1) v = fmaxf(v, __shfl_down(v, o));
  return v;
}
__device__ inline float waveMin(float v) {
#pragma unroll
  for (int o = 32; o > 0; o >>= 1) v = fminf(v, __shfl_down(v, o));
  return v;
}
__device__ inline float smooth_l1(float d) {
  d = fabsf(d);
  return d < 0.1f ? 5.0f * d * d : d - 0.05f;
}

// ws layout: float ws[0..6] partial losses; (uint)ws[7] global ticket;
//            uint bcnt[32] at ws+8; uint minarr[16384] at ws+40 (surf d^2)
// Grid: [0,64) chamfer+sep | [64,128) cov | [128,192) reg | 192 joint
//       [193,705) surf: s=bid-193, b=s>>4, chunk c=s&15 (512 pts);
//                 wave owns 128-pt slice, lane owns 8 nodes (lane+64q)
__global__ __launch_bounds__(256) void mega_kernel(
    const float* __restrict__ coefs,
    const float* __restrict__ preds,
    const float* __restrict__ nodes,
    const float* __restrict__ cloud,
    const int* __restrict__ cls,
    const float* __restrict__ pjl, const float* __restrict__ pja,
    const float* __restrict__ gjl, const float* __restrict__ gja,
    const float* __restrict__ gps,
    float* __restrict__ ws, float* __restrict__ out) {
  const int bid = blockIdx.x;
  const int t = threadIdx.x;
  const int wave = t >> 6, lane = t & 63;
  unsigned int* gcnt = (unsigned int*)(ws + 7);
  unsigned int* bcnt = (unsigned int*)(ws + 8);
  unsigned int* minarr = (unsigned int*)(ws + 40);
  __shared__ float4 sh4[512];     // 8 KB
  __shared__ float shg[4096];     // 16 KB (chamfer cross-wave combine)
  __shared__ float red[12][4];
  __shared__ int flagA, flagB;

  if (bid < 64) {
    // ---------------- chamfer + separation per (b,k) ----------------
    const int bk = bid;
    const float* pb = preds + (size_t)bk * PP * 3;
    const float* nbp = nodes + (size_t)bk * PP * 3;
    {
      float x = pb[3 * t], y = pb[3 * t + 1], z = pb[3 * t + 2];
      sh4[t] = make_float4(x, y, z, x * x + y * y + z * z);         // preds
      x = nbp[3 * t]; y = nbp[3 * t + 1]; z = nbp[3 * t + 2];
      sh4[256 + t] = make_float4(x, y, z, x * x + y * y + z * z);   // nodes
    }
    __syncthreads();
    float4 ptv[4], ntv[4];
#pragma unroll
    for (int q = 0; q < 4; ++q) {
      ptv[q] = sh4[lane + q * 64];
      ntv[q] = sh4[256 + lane + q * 64];
    }
    const float s0 = gps[bk * 3 + 0], s1 = gps[bk * 3 + 1], s2 = gps[bk * 3 + 2];
    const float thr = sqrtf(s0 * s0 + s1 * s1 + s2 * s2) * 0.125f;
    float g1[4], g2[4], sep = 0.0f;
#pragma unroll
    for (int q = 0; q < 4; ++q) { g1[q] = 1e30f; g2[q] = 1e30f; }
    const int j0 = wave * 64;
#pragma unroll 2
    for (int jj = 0; jj < 64; ++jj) {
      const int j = j0 + jj;
      const float4 pj = sh4[j];
      const float4 nj = sh4[256 + j];
#pragma unroll
      for (int q = 0; q < 4; ++q) {
        float dot = fmaf(ptv[q].x, nj.x, fmaf(ptv[q].y, nj.y, ptv[q].z * nj.z));
        g1[q] = fminf(g1[q], fmaf(-2.0f, dot, nj.w));
        dot = fmaf(ntv[q].x, pj.x, fmaf(ntv[q].y, pj.y, ntv[q].z * pj.z));
        g2[q] = fminf(g2[q], fmaf(-2.0f, dot, pj.w));
        dot = fmaf(ntv[q].x, nj.x, fmaf(ntv[q].y, nj.y, ntv[q].z * nj.z));
        const float d2 = fmaf(-2.0f, dot, ntv[q].w + nj.w);
        const float d = sqrtf(fmaxf(d2, 0.0f));
        if (j != lane + q * 64) sep += fmaxf(thr - d, 0.0f);
      }
    }
#pragma unroll
    for (int q = 0; q < 4; ++q) {
      shg[wave * 256 + lane + q * 64] = g1[q];
      shg[1024 + wave * 256 + lane + q * 64] = g2[q];
    }
    __syncthreads();
    const float gf = fminf(fminf(shg[t], shg[256 + t]),
                           fminf(shg[512 + t], shg[768 + t]));
    const float gb = fminf(fminf(shg[1024 + t], shg[1280 + t]),
                           fminf(shg[1536 + t], shg[1792 + t]));
    float chf = sqrtf(fmaxf(sh4[t].w + gf, 1e-12f)) +
                sqrtf(fmaxf(sh4[256 + t].w + gb, 1e-12f));
    chf = waveSum(chf);
    sep = waveSum(sep);
    if (lane == 0) { red[0][wave] = chf; red[1][wave] = sep; }
    __syncthreads();
    if (t == 0) {
      atomicAdd(&ws[0], red[0][0] + red[0][1] + red[0][2] + red[0][3]);
      atomicAdd(&ws[1], red[1][0] + red[1][1] + red[1][2] + red[1][3]);
    }

  } else if (bid < 128) {
    // ---------------- coverage per (b,k) ----------------
    const int bk = bid - 64;
    const int b = bk >> 1;
    const int k = bk & 1;
    float pmax0 = -1e9f, pmax1 = -1e9f, pmax2 = -1e9f;
    float pmin0 = 1e9f, pmin1 = 1e9f, pmin2 = 1e9f;
    const float* cb = cloud + (size_t)b * NCLOUD * 3;
    const int* lb = cls + (size_t)b * NCLOUD;
    for (int i = t; i < NCLOUD; i += 256) {
      if (lb[i] == k) {
        const float x = cb[i * 3 + 0], y = cb[i * 3 + 1], z = cb[i * 3 + 2];
        pmax0 = fmaxf(pmax0, x); pmax1 = fmaxf(pmax1, y); pmax2 = fmaxf(pmax2, z);
        pmin0 = fminf(pmin0, x); pmin1 = fminf(pmin1, y); pmin2 = fminf(pmin2, z);
      }
    }
    const float* nb = nodes + (size_t)bk * PP * 3;
    const float kx = nb[t * 3 + 0], ky = nb[t * 3 + 1], kz = nb[t * 3 + 2];
    pmax0 = waveMax(pmax0); pmax1 = waveMax(pmax1); pmax2 = waveMax(pmax2);
    pmin0 = waveMin(pmin0); pmin1 = waveMin(pmin1); pmin2 = waveMin(pmin2);
    float kmax0 = waveMax(kx), kmax1 = waveMax(ky), kmax2 = waveMax(kz);
    float kmin0 = waveMin(kx), kmin1 = waveMin(ky), kmin2 = waveMin(kz);
    if (lane == 0) {
      red[0][wave] = pmax0; red[1][wave] = pmax1; red[2][wave] = pmax2;
      red[3][wave] = pmin0; red[4][wave] = pmin1; red[5][wave] = pmin2;
      red[6][wave] = kmax0; red[7][wave] = kmax1; red[8][wave] = kmax2;
      red[9][wave] = kmin0; red[10][wave] = kmin1; red[11][wave] = kmin2;
    }
    __syncthreads();
    if (t == 0) {
      float v[12];
#pragma unroll
      for (int q = 0; q < 12; ++q) {
        if (q < 3 || (q >= 6 && q < 9))
          v[q] = fmaxf(fmaxf(red[q][0], red[q][1]), fmaxf(red[q][2], red[q][3]));
        else
          v[q] = fminf(fminf(red[q][0], red[q][1]), fminf(red[q][2], red[q][3]));
      }
      float s = 0.0f;
#pragma unroll
      for (int c2 = 0; c2 < 3; ++c2)
        s += 0.5f * (smooth_l1(v[6 + c2] - v[0 + c2]) + smooth_l1(v[9 + c2] - v[3 + c2]));
      atomicAdd(&ws[3], s);
    }

  } else if (bid < 192) {
    // ---------------- regularizer ----------------
    const int r = bid - 128;
    const float4* c4 = (const float4*)coefs;
    float v = 0.0f;
    for (int i = r * 256 + t; i < NCOEF / 4; i += 64 * 256) {
      const float4 q = c4[i];
      v += q.x * q.x + q.y * q.y + q.z * q.z + q.w * q.w;
    }
    v = waveSum(v);
    if (lane == 0) red[0][wave] = v;
    __syncthreads();
    if (t == 0)
      atomicAdd(&ws[6], red[0][0] + red[0][1] + red[0][2] + red[0][3]);

  } else if (bid == 192) {
    // ---------------- joint ----------------
    float cosv = 0.0f, locv = 0.0f;
    if (t < NB) {
      const float axj = pja[t * 3 + 0], ayj = pja[t * 3 + 1], azj = pja[t * 3 + 2];
      const float gx = gja[t * 3 + 0], gy = gja[t * 3 + 1], gz = gja[t * 3 + 2];
      const float dot = axj * gx + ayj * gy + azj * gz;
      const float na = sqrtf(axj * axj + ayj * ayj + azj * azj);
      const float nbn = sqrtf(gx * gx + gy * gy + gz * gz);
      cosv = dot / fmaxf(na * nbn, 1e-8f);
      const float ux = gx / nbn, uy = gy / nbn, uz = gz / nbn;
      const float px = gjl[t * 3 + 0], py = gjl[t * 3 + 1], pz = gjl[t * 3 + 2];
      const float qx = px + ux, qy = py + uy, qz = pz + uz;
      const float rx = pjl[t * 3 + 0], ry = pjl[t * 3 + 1], rz = pjl[t * 3 + 2];
      const float xx = px - qx, xy = py - qy, xz = pz - qz;
      const float tnum = (rx - qx) * xx + (ry - qy) * xy + (rz - qz) * xz;
      const float tden = xx * xx + xy * xy + xz * xz;
      const float tv = tnum / tden;
      const float vx = tv * xx + (qx - rx);
      const float vy = tv * xy + (qy - ry);
      const float vz = tv * xz + (qz - rz);
      locv = sqrtf(vx * vx + vy * vy + vz * vz);
    }
    cosv = waveSum(cosv);
    locv = waveSum(locv);
    if (t == 0) { atomicAdd(&ws[4], cosv); atomicAdd(&ws[5], locv); }

  } else {
    // ---------------- surf partial: (b, 512-pt chunk) ----------------
    const int s = bid - SURF0;
    const int b = s >> 4;
    const int c = s & 15;
    const float* cb = cloud + ((size_t)b * NCLOUD + (size_t)c * 512) * 3;
#pragma unroll
    for (int g = 0; g < 2; ++g) {
      const int idx = g * 256 + t;
      const float qx = cb[3 * idx], qy = cb[3 * idx + 1], qz = cb[3 * idx + 2];
      sh4[idx] = make_float4(qx, qy, qz, 0.5f * (qx * qx + qy * qy + qz * qz));
    }
    __syncthreads();
    const float* nb = nodes + (size_t)b * NNODES * 3;
    float nxv[8], nyv[8], nzv[8], nnv[8], mg[8];
#pragma unroll
    for (int q = 0; q < 8; ++q) {
      const int n = lane + q * 64;
      nxv[q] = nb[3 * n]; nyv[q] = nb[3 * n + 1]; nzv[q] = nb[3 * n + 2];
      nnv[q] = nxv[q] * nxv[q] + nyv[q] * nyv[q] + nzv[q] * nzv[q];
      mg[q] = 1e30f;
    }
    const int p0 = wave * 128;
#pragma unroll 4
    for (int j = 0; j < 128; ++j) {
      const float4 q4 = sh4[p0 + j];
#pragma unroll
      for (int q = 0; q < 8; ++q)
        mg[q] = fminf(mg[q],
                      fmaf(-nxv[q], q4.x,
                           fmaf(-nyv[q], q4.y, fmaf(-nzv[q], q4.z, q4.w))));
    }
#pragma unroll
    for (int q = 0; q < 8; ++q) {
      const unsigned int u = __float_as_uint(fmaxf(2.0f * mg[q] + nnv[q], 0.0f));
      unsigned int* p = &minarr[b * NNODES + lane + q * 64];
      if (*p > u) atomicMin(p, u);   // stale read >= current: skip is safe
    }
    // per-batch ticket: 16th chunk-block reduces this batch's 512 mins
    __threadfence();
    __syncthreads();
    if (t == 0) flagB = (atomicAdd(&bcnt[b], 1u) == (NCHUNK - 1));
    __syncthreads();
    if (flagB) {
      __threadfence();  // acquire
      const uint2 v = *(const uint2*)&minarr[b * NNODES + 2 * t];
      float ssum = sqrtf(fmaxf(__uint_as_float(v.x), 1e-12f)) +
                   sqrtf(fmaxf(__uint_as_float(v.y), 1e-12f));
      ssum = waveSum(ssum);
      if (lane == 0) red[2][wave] = ssum;
      __syncthreads();
      if (t == 0)
        atomicAdd(&ws[2], red[2][0] + red[2][1] + red[2][2] + red[2][3]);
    }
  }

  // ---------------- global ticket: last block combines scalars ----------------
  __threadfence();
  __syncthreads();
  if (t == 0)
    flagA = (atomicAdd(gcnt, 1u) == (unsigned int)(NBLK - 1));
  __syncthreads();
  if (flagA && t == 0) {
    __threadfence();  // acquire
    const float chf = ws[0] / (float)(KK * NB * PP);
    const float sep = ws[1] / (float)(NB * KK * PP * (PP - 1));
    const float surf = ws[2] / (float)(NB * NNODES);
    const float cov = ws[3] / (float)(NB * KK * 3);
    const float axis = 1.0f - ws[4] / (float)NB;
    const float loc = ws[5] / (float)NB;
    const float reg = ws[6] / (float)NCOEF;
    out[0] = chf + cov + surf * 5.0f + (loc + 0.5f * axis) + reg * 0.01f + sep * 2.0f;
  }
}

extern "C" void kernel_launch(void* const* d_in, const int* in_sizes, int n_in,
                              void* d_out, int out_size, void* d_ws, size_t ws_size,
                              hipStream_t stream) {
  const float* coefs = (const float*)d_in[0];
  const float* preds = (const float*)d_in[1];
  const float* nodes = (const float*)d_in[2];
  const float* cloud = (const float*)d_in[3];
  const int* cls = (const int*)d_in[4];
  const float* pjl = (const float*)d_in[5];
  const float* pja = (const float*)d_in[6];
  const float* gjl = (const float*)d_in[7];
  const float* gja = (const float*)d_in[8];
  const float* gps = (const float*)d_in[9];
  float* out = (float*)d_out;
  float* ws = (float*)d_ws;

  // zero scalars + counters (40 floats), set minarr (16384 uints) to 0xFF
  hipMemsetAsync(ws, 0, 40 * sizeof(float), stream);
  hipMemsetAsync(ws + 40, 0xFF, NB * NNODES * sizeof(unsigned int), stream);
  mega_kernel<<<NBLK, 256, 0, stream>>>(coefs, preds, nodes, cloud, cls,
                                        pjl, pja, gjl, gja, gps, ws, out);
}

// Round 7
// 48.203 us; speedup vs baseline: 2.3114x; 2.3114x over previous
//
#include <hip/hip_runtime.h>
#include <math.h>

#define NB 32
#define KK 2
#define PP 256
#define NCLOUD 8192
#define NNODES 512   // K*P
#define NCOEF 163840 // B*K*P*COEF_D
#define SURF0 193
#define NCHUNK 16                 // chunks per batch (512 pts each)
#define NSURF (NB * NCHUNK)       // 512
#define NBLK (SURF0 + NSURF)      // 705

__device__ inline float waveSum(float v) {
#pragma unroll
  for (int o = 32; o > 0; o >>= 1) v += __shfl_down(v, o);
  return v;
}
__device__ inline float waveMax(float v) {
#pragma unroll
  for (int o = 32; o > 0; o >>= 1) v = fmaxf(v, __shfl_down(v, o));
  return v;
}
__device__ inline float waveMin(float v) {
#pragma unroll
  for (int o = 32; o > 0; o >>= 1) v = fminf(v, __shfl_down(v, o));
  return v;
}
__device__ inline float smooth_l1(float d) {
  d = fabsf(d);
  return d < 0.1f ? 5.0f * d * d : d - 0.05f;
}

// ws layout: float ws[0..6] partial losses; uint minarr[16384] at ws+8 (surf d^2)
// Grid: [0,64) chamfer+sep | [64,128) cov | [128,192) reg | 192 joint
//       [193,705) surf: s=bid-193, b=s>>4, chunk c=s&15 (512 pts);
//                 wave owns 128-pt slice, lane owns 8 nodes (lane+64q)
// NO tickets, NO __threadfence: cross-block combination happens in final_kernel
// (kernel boundary on the stream provides the ordering/visibility).
__global__ __launch_bounds__(256) void mega_kernel(
    const float* __restrict__ coefs,
    const float* __restrict__ preds,
    const float* __restrict__ nodes,
    const float* __restrict__ cloud,
    const int* __restrict__ cls,
    const float* __restrict__ pjl, const float* __restrict__ pja,
    const float* __restrict__ gjl, const float* __restrict__ gja,
    const float* __restrict__ gps,
    float* __restrict__ ws) {
  const int bid = blockIdx.x;
  const int t = threadIdx.x;
  const int wave = t >> 6, lane = t & 63;
  unsigned int* minarr = (unsigned int*)(ws + 8);
  __shared__ float4 sh4[512];     // 8 KB
  __shared__ float shg[2048];     // 8 KB (chamfer cross-wave min combine)
  __shared__ float red[12][4];

  if (bid < 64) {
    // ---------------- chamfer + separation per (b,k) ----------------
    const int bk = bid;
    const float* pb = preds + (size_t)bk * PP * 3;
    const float* nbp = nodes + (size_t)bk * PP * 3;
    {
      float x = pb[3 * t], y = pb[3 * t + 1], z = pb[3 * t + 2];
      sh4[t] = make_float4(x, y, z, x * x + y * y + z * z);         // preds
      x = nbp[3 * t]; y = nbp[3 * t + 1]; z = nbp[3 * t + 2];
      sh4[256 + t] = make_float4(x, y, z, x * x + y * y + z * z);   // nodes
    }
    __syncthreads();
    float4 ptv[4], ntv[4];
#pragma unroll
    for (int q = 0; q < 4; ++q) {
      ptv[q] = sh4[lane + q * 64];
      ntv[q] = sh4[256 + lane + q * 64];
    }
    const float s0 = gps[bk * 3 + 0], s1 = gps[bk * 3 + 1], s2 = gps[bk * 3 + 2];
    const float thr = sqrtf(s0 * s0 + s1 * s1 + s2 * s2) * 0.125f;
    float g1[4], g2[4], sep = 0.0f;
#pragma unroll
    for (int q = 0; q < 4; ++q) { g1[q] = 1e30f; g2[q] = 1e30f; }
    const int j0 = wave * 64;
#pragma unroll 2
    for (int jj = 0; jj < 64; ++jj) {
      const int j = j0 + jj;
      const float4 pj = sh4[j];
      const float4 nj = sh4[256 + j];
#pragma unroll
      for (int q = 0; q < 4; ++q) {
        float dot = fmaf(ptv[q].x, nj.x, fmaf(ptv[q].y, nj.y, ptv[q].z * nj.z));
        g1[q] = fminf(g1[q], fmaf(-2.0f, dot, nj.w));
        dot = fmaf(ntv[q].x, pj.x, fmaf(ntv[q].y, pj.y, ntv[q].z * pj.z));
        g2[q] = fminf(g2[q], fmaf(-2.0f, dot, pj.w));
        dot = fmaf(ntv[q].x, nj.x, fmaf(ntv[q].y, nj.y, ntv[q].z * nj.z));
        const float d2 = fmaf(-2.0f, dot, ntv[q].w + nj.w);
        const float d = sqrtf(fmaxf(d2, 0.0f));
        if (j != lane + q * 64) sep += fmaxf(thr - d, 0.0f);
      }
    }
#pragma unroll
    for (int q = 0; q < 4; ++q) {
      shg[wave * 256 + lane + q * 64] = g1[q];
      shg[1024 + wave * 256 + lane + q * 64] = g2[q];
    }
    __syncthreads();
    const float gf = fminf(fminf(shg[t], shg[256 + t]),
                           fminf(shg[512 + t], shg[768 + t]));
    const float gb = fminf(fminf(shg[1024 + t], shg[1280 + t]),
                           fminf(shg[1536 + t], shg[1792 + t]));
    float chf = sqrtf(fmaxf(sh4[t].w + gf, 1e-12f)) +
                sqrtf(fmaxf(sh4[256 + t].w + gb, 1e-12f));
    chf = waveSum(chf);
    sep = waveSum(sep);
    if (lane == 0) { red[0][wave] = chf; red[1][wave] = sep; }
    __syncthreads();
    if (t == 0) {
      atomicAdd(&ws[0], red[0][0] + red[0][1] + red[0][2] + red[0][3]);
      atomicAdd(&ws[1], red[1][0] + red[1][1] + red[1][2] + red[1][3]);
    }

  } else if (bid < 128) {
    // ---------------- coverage per (b,k) ----------------
    const int bk = bid - 64;
    const int b = bk >> 1;
    const int k = bk & 1;
    float pmax0 = -1e9f, pmax1 = -1e9f, pmax2 = -1e9f;
    float pmin0 = 1e9f, pmin1 = 1e9f, pmin2 = 1e9f;
    const float* cb = cloud + (size_t)b * NCLOUD * 3;
    const int* lb = cls + (size_t)b * NCLOUD;
    for (int i = t; i < NCLOUD; i += 256) {
      if (lb[i] == k) {
        const float x = cb[i * 3 + 0], y = cb[i * 3 + 1], z = cb[i * 3 + 2];
        pmax0 = fmaxf(pmax0, x); pmax1 = fmaxf(pmax1, y); pmax2 = fmaxf(pmax2, z);
        pmin0 = fminf(pmin0, x); pmin1 = fminf(pmin1, y); pmin2 = fminf(pmin2, z);
      }
    }
    const float* nb = nodes + (size_t)bk * PP * 3;
    const float kx = nb[t * 3 + 0], ky = nb[t * 3 + 1], kz = nb[t * 3 + 2];
    pmax0 = waveMax(pmax0); pmax1 = waveMax(pmax1); pmax2 = waveMax(pmax2);
    pmin0 = waveMin(pmin0); pmin1 = waveMin(pmin1); pmin2 = waveMin(pmin2);
    float kmax0 = waveMax(kx), kmax1 = waveMax(ky), kmax2 = waveMax(kz);
    float kmin0 = waveMin(kx), kmin1 = waveMin(ky), kmin2 = waveMin(kz);
    if (lane == 0) {
      red[0][wave] = pmax0; red[1][wave] = pmax1; red[2][wave] = pmax2;
      red[3][wave] = pmin0; red[4][wave] = pmin1; red[5][wave] = pmin2;
      red[6][wave] = kmax0; red[7][wave] = kmax1; red[8][wave] = kmax2;
      red[9][wave] = kmin0; red[10][wave] = kmin1; red[11][wave] = kmin2;
    }
    __syncthreads();
    if (t == 0) {
      float v[12];
#pragma unroll
      for (int q = 0; q < 12; ++q) {
        if (q < 3 || (q >= 6 && q < 9))
          v[q] = fmaxf(fmaxf(red[q][0], red[q][1]), fmaxf(red[q][2], red[q][3]));
        else
          v[q] = fminf(fminf(red[q][0], red[q][1]), fminf(red[q][2], red[q][3]));
      }
      float s = 0.0f;
#pragma unroll
      for (int c2 = 0; c2 < 3; ++c2)
        s += 0.5f * (smooth_l1(v[6 + c2] - v[0 + c2]) + smooth_l1(v[9 + c2] - v[3 + c2]));
      atomicAdd(&ws[3], s);
    }

  } else if (bid < 192) {
    // ---------------- regularizer ----------------
    const int r = bid - 128;
    const float4* c4 = (const float4*)coefs;
    float v = 0.0f;
    for (int i = r * 256 + t; i < NCOEF / 4; i += 64 * 256) {
      const float4 q = c4[i];
      v += q.x * q.x + q.y * q.y + q.z * q.z + q.w * q.w;
    }
    v = waveSum(v);
    if (lane == 0) red[0][wave] = v;
    __syncthreads();
    if (t == 0)
      atomicAdd(&ws[6], red[0][0] + red[0][1] + red[0][2] + red[0][3]);

  } else if (bid == 192) {
    // ---------------- joint ----------------
    float cosv = 0.0f, locv = 0.0f;
    if (t < NB) {
      const float axj = pja[t * 3 + 0], ayj = pja[t * 3 + 1], azj = pja[t * 3 + 2];
      const float gx = gja[t * 3 + 0], gy = gja[t * 3 + 1], gz = gja[t * 3 + 2];
      const float dot = axj * gx + ayj * gy + azj * gz;
      const float na = sqrtf(axj * axj + ayj * ayj + azj * azj);
      const float nbn = sqrtf(gx * gx + gy * gy + gz * gz);
      cosv = dot / fmaxf(na * nbn, 1e-8f);
      const float ux = gx / nbn, uy = gy / nbn, uz = gz / nbn;
      const float px = gjl[t * 3 + 0], py = gjl[t * 3 + 1], pz = gjl[t * 3 + 2];
      const float qx = px + ux, qy = py + uy, qz = pz + uz;
      const float rx = pjl[t * 3 + 0], ry = pjl[t * 3 + 1], rz = pjl[t * 3 + 2];
      const float xx = px - qx, xy = py - qy, xz = pz - qz;
      const float tnum = (rx - qx) * xx + (ry - qy) * xy + (rz - qz) * xz;
      const float tden = xx * xx + xy * xy + xz * xz;
      const float tv = tnum / tden;
      const float vx = tv * xx + (qx - rx);
      const float vy = tv * xy + (qy - ry);
      const float vz = tv * xz + (qz - rz);
      locv = sqrtf(vx * vx + vy * vy + vz * vz);
    }
    cosv = waveSum(cosv);
    locv = waveSum(locv);
    if (t == 0) { atomicAdd(&ws[4], cosv); atomicAdd(&ws[5], locv); }

  } else {
    // ---------------- surf partial: (b, 512-pt chunk) ----------------
    const int s = bid - SURF0;
    const int b = s >> 4;
    const int c = s & 15;
    const float* cb = cloud + ((size_t)b * NCLOUD + (size_t)c * 512) * 3;
#pragma unroll
    for (int g = 0; g < 2; ++g) {
      const int idx = g * 256 + t;
      const float qx = cb[3 * idx], qy = cb[3 * idx + 1], qz = cb[3 * idx + 2];
      sh4[idx] = make_float4(qx, qy, qz, 0.5f * (qx * qx + qy * qy + qz * qz));
    }
    __syncthreads();
    const float* nb = nodes + (size_t)b * NNODES * 3;
    float nxv[8], nyv[8], nzv[8], nnv[8], mg[8];
#pragma unroll
    for (int q = 0; q < 8; ++q) {
      const int n = lane + q * 64;
      nxv[q] = nb[3 * n]; nyv[q] = nb[3 * n + 1]; nzv[q] = nb[3 * n + 2];
      nnv[q] = nxv[q] * nxv[q] + nyv[q] * nyv[q] + nzv[q] * nzv[q];
      mg[q] = 1e30f;
    }
    const int p0 = wave * 128;
#pragma unroll 4
    for (int j = 0; j < 128; ++j) {
      const float4 q4 = sh4[p0 + j];
#pragma unroll
      for (int q = 0; q < 8; ++q)
        mg[q] = fminf(mg[q],
                      fmaf(-nxv[q], q4.x,
                           fmaf(-nyv[q], q4.y, fmaf(-nzv[q], q4.z, q4.w))));
    }
#pragma unroll
    for (int q = 0; q < 8; ++q) {
      const unsigned int u = __float_as_uint(fmaxf(2.0f * mg[q] + nnv[q], 0.0f));
      unsigned int* p = &minarr[b * NNODES + lane + q * 64];
      if (*p > u) atomicMin(p, u);   // stale read >= current: skip is safe
    }
  }
}

// ---------------- final: reduce surf min-array + combine ----------------
__global__ __launch_bounds__(1024) void final_kernel(
    const float* __restrict__ ws, float* __restrict__ out) {
  const int t = threadIdx.x;
  const unsigned int* minarr = (const unsigned int*)(ws + 8);
  float s = 0.0f;
  const uint4* m4 = (const uint4*)minarr;
  for (int i = t; i < NB * NNODES / 4; i += 1024) {
    const uint4 v = m4[i];
    s += sqrtf(fmaxf(__uint_as_float(v.x), 1e-12f)) +
         sqrtf(fmaxf(__uint_as_float(v.y), 1e-12f)) +
         sqrtf(fmaxf(__uint_as_float(v.z), 1e-12f)) +
         sqrtf(fmaxf(__uint_as_float(v.w), 1e-12f));
  }
  s = waveSum(s);
  __shared__ float r[16];
  const int wave = t >> 6, lane = t & 63;
  if (lane == 0) r[wave] = s;
  __syncthreads();
  if (t == 0) {
    float surf_sum = 0.0f;
#pragma unroll
    for (int q = 0; q < 16; ++q) surf_sum += r[q];
    const float chf = ws[0] / (float)(KK * NB * PP);
    const float sep = ws[1] / (float)(NB * KK * PP * (PP - 1));
    const float surf = surf_sum / (float)(NB * NNODES);
    const float cov = ws[3] / (float)(NB * KK * 3);
    const float axis = 1.0f - ws[4] / (float)NB;
    const float loc = ws[5] / (float)NB;
    const float reg = ws[6] / (float)NCOEF;
    out[0] = chf + cov + surf * 5.0f + (loc + 0.5f * axis) + reg * 0.01f + sep * 2.0f;
  }
}

extern "C" void kernel_launch(void* const* d_in, const int* in_sizes, int n_in,
                              void* d_out, int out_size, void* d_ws, size_t ws_size,
                              hipStream_t stream) {
  const float* coefs = (const float*)d_in[0];
  const float* preds = (const float*)d_in[1];
  const float* nodes = (const float*)d_in[2];
  const float* cloud = (const float*)d_in[3];
  const int* cls = (const int*)d_in[4];
  const float* pjl = (const float*)d_in[5];
  const float* pja = (const float*)d_in[6];
  const float* gjl = (const float*)d_in[7];
  const float* gja = (const float*)d_in[8];
  const float* gps = (const float*)d_in[9];
  float* out = (float*)d_out;
  float* ws = (float*)d_ws;

  hipMemsetAsync(ws, 0, 8 * sizeof(float), stream);
  hipMemsetAsync(ws + 8, 0xFF, NB * NNODES * sizeof(unsigned int), stream);
  mega_kernel<<<NBLK, 256, 0, stream>>>(coefs, preds, nodes, cloud, cls,
                                        pjl, pja, gjl, gja, gps, ws);
  final_kernel<<<1, 1024, 0, stream>>>(ws, out);
}

// Round 8
// 35.372 us; speedup vs baseline: 3.1499x; 1.3627x over previous
//
#include <hip/hip_runtime.h>
#include <math.h>

#define NB 32
#define KK 2
#define PP 256
#define NCLOUD 8192
#define NNODES 512   // K*P
#define NCOEF 163840 // B*K*P*COEF_D
#define SURF0 193
#define NCHUNK 16                 // chunks per batch (512 pts each)
#define NSURF (NB * NCHUNK)       // 512
#define NBLK (SURF0 + NSURF)      // 705

__device__ inline float waveSum(float v) {
#pragma unroll
  for (int o = 32; o > 0; o >>= 1) v += __shfl_down(v, o);
  return v;
}
__device__ inline float waveMax(float v) {
#pragma unroll
  for (int o = 32; o > 0; o >>= 1) v = fmaxf(v, __shfl_down(v, o));
  return v;
}
__device__ inline float waveMin(float v) {
#pragma unroll
  for (int o = 32; o > 0; o >>= 1) v = fminf(v, __shfl_down(v, o));
  return v;
}
__device__ inline float smooth_l1(float d) {
  d = fabsf(d);
  return d < 0.1f ? 5.0f * d * d : d - 0.05f;
}

// ws layout: float ws[0..6] partial losses; float partial[32][16][512] at ws+8
// (per-batch, per-chunk min d^2 per node; fully overwritten every call).
// Grid: [0,64) chamfer+sep | [64,128) cov | [128,192) reg | 192 joint
//       [193,705) surf: s=bid-193, b=s>>4, chunk c=s&15 (512 pts);
//                 wave owns 128-pt slice, lane owns 8 nodes (lane+64q)
// NO atomics on vector data, NO __threadfence. Cross-block combining happens in
// final kernels (stream kernel-boundary ordering).
__global__ __launch_bounds__(256) void mega_kernel(
    const float* __restrict__ coefs,
    const float* __restrict__ preds,
    const float* __restrict__ nodes,
    const float* __restrict__ cloud,
    const int* __restrict__ cls,
    const float* __restrict__ pjl, const float* __restrict__ pja,
    const float* __restrict__ gjl, const float* __restrict__ gja,
    const float* __restrict__ gps,
    float* __restrict__ ws) {
  const int bid = blockIdx.x;
  const int t = threadIdx.x;
  const int wave = t >> 6, lane = t & 63;
  float* partial = ws + 8;
  __shared__ float4 sh4[512];     // 8 KB
  __shared__ float shg[2048];     // 8 KB (cross-wave combine)
  __shared__ float red[12][4];

  if (bid < 64) {
    // ---------------- chamfer + separation per (b,k) ----------------
    const int bk = bid;
    const float* pb = preds + (size_t)bk * PP * 3;
    const float* nbp = nodes + (size_t)bk * PP * 3;
    {
      float x = pb[3 * t], y = pb[3 * t + 1], z = pb[3 * t + 2];
      sh4[t] = make_float4(x, y, z, x * x + y * y + z * z);         // preds
      x = nbp[3 * t]; y = nbp[3 * t + 1]; z = nbp[3 * t + 2];
      sh4[256 + t] = make_float4(x, y, z, x * x + y * y + z * z);   // nodes
    }
    __syncthreads();
    float4 ptv[4], ntv[4];
#pragma unroll
    for (int q = 0; q < 4; ++q) {
      ptv[q] = sh4[lane + q * 64];
      ntv[q] = sh4[256 + lane + q * 64];
    }
    const float s0 = gps[bk * 3 + 0], s1 = gps[bk * 3 + 1], s2 = gps[bk * 3 + 2];
    const float thr = sqrtf(s0 * s0 + s1 * s1 + s2 * s2) * 0.125f;
    float g1[4], g2[4], sep = 0.0f;
#pragma unroll
    for (int q = 0; q < 4; ++q) { g1[q] = 1e30f; g2[q] = 1e30f; }
    const int j0 = wave * 64;
#pragma unroll 2
    for (int jj = 0; jj < 64; ++jj) {
      const int j = j0 + jj;
      const float4 pj = sh4[j];
      const float4 nj = sh4[256 + j];
#pragma unroll
      for (int q = 0; q < 4; ++q) {
        float dot = fmaf(ptv[q].x, nj.x, fmaf(ptv[q].y, nj.y, ptv[q].z * nj.z));
        g1[q] = fminf(g1[q], fmaf(-2.0f, dot, nj.w));
        dot = fmaf(ntv[q].x, pj.x, fmaf(ntv[q].y, pj.y, ntv[q].z * pj.z));
        g2[q] = fminf(g2[q], fmaf(-2.0f, dot, pj.w));
        dot = fmaf(ntv[q].x, nj.x, fmaf(ntv[q].y, nj.y, ntv[q].z * nj.z));
        const float d2 = fmaf(-2.0f, dot, ntv[q].w + nj.w);
        const float d = sqrtf(fmaxf(d2, 0.0f));
        if (j != lane + q * 64) sep += fmaxf(thr - d, 0.0f);
      }
    }
#pragma unroll
    for (int q = 0; q < 4; ++q) {
      shg[wave * 256 + lane + q * 64] = g1[q];
      shg[1024 + wave * 256 + lane + q * 64] = g2[q];
    }
    __syncthreads();
    const float gf = fminf(fminf(shg[t], shg[256 + t]),
                           fminf(shg[512 + t], shg[768 + t]));
    const float gb = fminf(fminf(shg[1024 + t], shg[1280 + t]),
                           fminf(shg[1536 + t], shg[1792 + t]));
    float chf = sqrtf(fmaxf(sh4[t].w + gf, 1e-12f)) +
                sqrtf(fmaxf(sh4[256 + t].w + gb, 1e-12f));
    chf = waveSum(chf);
    sep = waveSum(sep);
    if (lane == 0) { red[0][wave] = chf; red[1][wave] = sep; }
    __syncthreads();
    if (t == 0) {
      atomicAdd(&ws[0], red[0][0] + red[0][1] + red[0][2] + red[0][3]);
      atomicAdd(&ws[1], red[1][0] + red[1][1] + red[1][2] + red[1][3]);
    }

  } else if (bid < 128) {
    // ---------------- coverage per (b,k) ----------------
    const int bk = bid - 64;
    const int b = bk >> 1;
    const int k = bk & 1;
    float pmax0 = -1e9f, pmax1 = -1e9f, pmax2 = -1e9f;
    float pmin0 = 1e9f, pmin1 = 1e9f, pmin2 = 1e9f;
    const float* cb = cloud + (size_t)b * NCLOUD * 3;
    const int* lb = cls + (size_t)b * NCLOUD;
    for (int i = t; i < NCLOUD; i += 256) {
      if (lb[i] == k) {
        const float x = cb[i * 3 + 0], y = cb[i * 3 + 1], z = cb[i * 3 + 2];
        pmax0 = fmaxf(pmax0, x); pmax1 = fmaxf(pmax1, y); pmax2 = fmaxf(pmax2, z);
        pmin0 = fminf(pmin0, x); pmin1 = fminf(pmin1, y); pmin2 = fminf(pmin2, z);
      }
    }
    const float* nb = nodes + (size_t)bk * PP * 3;
    const float kx = nb[t * 3 + 0], ky = nb[t * 3 + 1], kz = nb[t * 3 + 2];
    pmax0 = waveMax(pmax0); pmax1 = waveMax(pmax1); pmax2 = waveMax(pmax2);
    pmin0 = waveMin(pmin0); pmin1 = waveMin(pmin1); pmin2 = waveMin(pmin2);
    float kmax0 = waveMax(kx), kmax1 = waveMax(ky), kmax2 = waveMax(kz);
    float kmin0 = waveMin(kx), kmin1 = waveMin(ky), kmin2 = waveMin(kz);
    if (lane == 0) {
      red[0][wave] = pmax0; red[1][wave] = pmax1; red[2][wave] = pmax2;
      red[3][wave] = pmin0; red[4][wave] = pmin1; red[5][wave] = pmin2;
      red[6][wave] = kmax0; red[7][wave] = kmax1; red[8][wave] = kmax2;
      red[9][wave] = kmin0; red[10][wave] = kmin1; red[11][wave] = kmin2;
    }
    __syncthreads();
    if (t == 0) {
      float v[12];
#pragma unroll
      for (int q = 0; q < 12; ++q) {
        if (q < 3 || (q >= 6 && q < 9))
          v[q] = fmaxf(fmaxf(red[q][0], red[q][1]), fmaxf(red[q][2], red[q][3]));
        else
          v[q] = fminf(fminf(red[q][0], red[q][1]), fminf(red[q][2], red[q][3]));
      }
      float s = 0.0f;
#pragma unroll
      for (int c2 = 0; c2 < 3; ++c2)
        s += 0.5f * (smooth_l1(v[6 + c2] - v[0 + c2]) + smooth_l1(v[9 + c2] - v[3 + c2]));
      atomicAdd(&ws[3], s);
    }

  } else if (bid < 192) {
    // ---------------- regularizer ----------------
    const int r = bid - 128;
    const float4* c4 = (const float4*)coefs;
    float v = 0.0f;
    for (int i = r * 256 + t; i < NCOEF / 4; i += 64 * 256) {
      const float4 q = c4[i];
      v += q.x * q.x + q.y * q.y + q.z * q.z + q.w * q.w;
    }
    v = waveSum(v);
    if (lane == 0) red[0][wave] = v;
    __syncthreads();
    if (t == 0)
      atomicAdd(&ws[6], red[0][0] + red[0][1] + red[0][2] + red[0][3]);

  } else if (bid == 192) {
    // ---------------- joint ----------------
    float cosv = 0.0f, locv = 0.0f;
    if (t < NB) {
      const float axj = pja[t * 3 + 0], ayj = pja[t * 3 + 1], azj = pja[t * 3 + 2];
      const float gx = gja[t * 3 + 0], gy = gja[t * 3 + 1], gz = gja[t * 3 + 2];
      const float dot = axj * gx + ayj * gy + azj * gz;
      const float na = sqrtf(axj * axj + ayj * ayj + azj * azj);
      const float nbn = sqrtf(gx * gx + gy * gy + gz * gz);
      cosv = dot / fmaxf(na * nbn, 1e-8f);
      const float ux = gx / nbn, uy = gy / nbn, uz = gz / nbn;
      const float px = gjl[t * 3 + 0], py = gjl[t * 3 + 1], pz = gjl[t * 3 + 2];
      const float qx = px + ux, qy = py + uy, qz = pz + uz;
      const float rx = pjl[t * 3 + 0], ry = pjl[t * 3 + 1], rz = pjl[t * 3 + 2];
      const float xx = px - qx, xy = py - qy, xz = pz - qz;
      const float tnum = (rx - qx) * xx + (ry - qy) * xy + (rz - qz) * xz;
      const float tden = xx * xx + xy * xy + xz * xz;
      const float tv = tnum / tden;
      const float vx = tv * xx + (qx - rx);
      const float vy = tv * xy + (qy - ry);
      const float vz = tv * xz + (qz - rz);
      locv = sqrtf(vx * vx + vy * vy + vz * vz);
    }
    cosv = waveSum(cosv);
    locv = waveSum(locv);
    if (t == 0) { atomicAdd(&ws[4], cosv); atomicAdd(&ws[5], locv); }

  } else {
    // ---------------- surf partial: (b, 512-pt chunk) ----------------
    const int s = bid - SURF0;
    const int b = s >> 4;
    const int c = s & 15;
    const float* cb = cloud + ((size_t)b * NCLOUD + (size_t)c * 512) * 3;
#pragma unroll
    for (int g = 0; g < 2; ++g) {
      const int idx = g * 256 + t;
      const float qx = cb[3 * idx], qy = cb[3 * idx + 1], qz = cb[3 * idx + 2];
      sh4[idx] = make_float4(qx, qy, qz, 0.5f * (qx * qx + qy * qy + qz * qz));
    }
    __syncthreads();
    const float* nb = nodes + (size_t)b * NNODES * 3;
    float nxv[8], nyv[8], nzv[8], nnv[8], mg[8];
#pragma unroll
    for (int q = 0; q < 8; ++q) {
      const int n = lane + q * 64;
      nxv[q] = nb[3 * n]; nyv[q] = nb[3 * n + 1]; nzv[q] = nb[3 * n + 2];
      nnv[q] = nxv[q] * nxv[q] + nyv[q] * nyv[q] + nzv[q] * nzv[q];
      mg[q] = 1e30f;
    }
    const int p0 = wave * 128;
#pragma unroll 4
    for (int j = 0; j < 128; ++j) {
      const float4 q4 = sh4[p0 + j];
#pragma unroll
      for (int q = 0; q < 8; ++q)
        mg[q] = fminf(mg[q],
                      fmaf(-nxv[q], q4.x,
                           fmaf(-nyv[q], q4.y, fmaf(-nzv[q], q4.z, q4.w))));
    }
    // cross-wave min combine in LDS, then coalesced store (no atomics)
#pragma unroll
    for (int q = 0; q < 8; ++q)
      shg[wave * 512 + lane + q * 64] = mg[q];
    __syncthreads();
    float* pout = partial + ((size_t)b * NCHUNK + c) * NNODES;
#pragma unroll
    for (int g = 0; g < 2; ++g) {
      const int node = g * 256 + t;
      const float m = fminf(fminf(shg[node], shg[512 + node]),
                            fminf(shg[1024 + node], shg[1536 + node]));
      // nn for this node: recompute from nodes (cheap, coalesced-ish)
      const float x = nb[3 * node], y = nb[3 * node + 1], z = nb[3 * node + 2];
      const float nn = x * x + y * y + z * z;
      pout[node] = fmaxf(fmaf(2.0f, m, nn), 0.0f);
    }
  }
}

// ---------------- final1: per-batch min over chunks -> sqrt-sum ----------------
__global__ __launch_bounds__(256) void final1_kernel(float* __restrict__ ws) {
  const int b = blockIdx.x;
  const int t = threadIdx.x;
  const float* partial = ws + 8;
  float ssum = 0.0f;
#pragma unroll
  for (int g = 0; g < 2; ++g) {
    const int node = g * 256 + t;
    float m = 1e30f;
#pragma unroll
    for (int c = 0; c < NCHUNK; ++c)
      m = fminf(m, partial[((size_t)b * NCHUNK + c) * NNODES + node]);
    ssum += sqrtf(fmaxf(m, 1e-12f));
  }
  ssum = waveSum(ssum);
  __shared__ float r[4];
  const int wave = t >> 6, lane = t & 63;
  if (lane == 0) r[wave] = ssum;
  __syncthreads();
  if (t == 0) atomicAdd(&ws[2], r[0] + r[1] + r[2] + r[3]);
}

// ---------------- final2: combine scalars ----------------
__global__ void final2_kernel(const float* __restrict__ ws, float* __restrict__ out) {
  const float chf = ws[0] / (float)(KK * NB * PP);
  const float sep = ws[1] / (float)(NB * KK * PP * (PP - 1));
  const float surf = ws[2] / (float)(NB * NNODES);
  const float cov = ws[3] / (float)(NB * KK * 3);
  const float axis = 1.0f - ws[4] / (float)NB;
  const float loc = ws[5] / (float)NB;
  const float reg = ws[6] / (float)NCOEF;
  out[0] = chf + cov + surf * 5.0f + (loc + 0.5f * axis) + reg * 0.01f + sep * 2.0f;
}

extern "C" void kernel_launch(void* const* d_in, const int* in_sizes, int n_in,
                              void* d_out, int out_size, void* d_ws, size_t ws_size,
                              hipStream_t stream) {
  const float* coefs = (const float*)d_in[0];
  const float* preds = (const float*)d_in[1];
  const float* nodes = (const float*)d_in[2];
  const float* cloud = (const float*)d_in[3];
  const int* cls = (const int*)d_in[4];
  const float* pjl = (const float*)d_in[5];
  const float* pja = (const float*)d_in[6];
  const float* gjl = (const float*)d_in[7];
  const float* gja = (const float*)d_in[8];
  const float* gps = (const float*)d_in[9];
  float* out = (float*)d_out;
  float* ws = (float*)d_ws;

  hipMemsetAsync(ws, 0, 8 * sizeof(float), stream);
  mega_kernel<<<NBLK, 256, 0, stream>>>(coefs, preds, nodes, cloud, cls,
                                        pjl, pja, gjl, gja, gps, ws);
  final1_kernel<<<NB, 256, 0, stream>>>(ws);
  final2_kernel<<<1, 1, 0, stream>>>(ws, out);
}

// Round 9
// 29.504 us; speedup vs baseline: 3.7764x; 1.1989x over previous
//
#include <hip/hip_runtime.h>
#include <math.h>

#define NB 32
#define KK 2
#define PP 256
#define NCLOUD 8192
#define NNODES 512   // K*P
#define NCOEF 163840 // B*K*P*COEF_D
#define SURF0 193
#define NCHUNK 16                 // chunks per batch (512 pts each)
#define NSURF (NB * NCHUNK)       // 512
#define NBLK (SURF0 + NSURF)      // 705

// ws float slot layout (all written every call; no memset, no atomics):
//   [0,64)    chf per chamfer block
//   [64,128)  sep per chamfer block
//   [128,192) cov per (b,k) block
//   [192,256) reg per block
//   [256]     cosv  [257] locv
//   [258,290) sbatch per batch (final1 out)
//   [320, 320+32*16*512) partial min-g per (b,chunk,node)
#define SL_CHF 0
#define SL_SEP 64
#define SL_COV 128
#define SL_REG 192
#define SL_JNT 256
#define SL_SB 258
#define PART0 320

__device__ inline float waveSum(float v) {
#pragma unroll
  for (int o = 32; o > 0; o >>= 1) v += __shfl_down(v, o);
  return v;
}
__device__ inline float waveMax(float v) {
#pragma unroll
  for (int o = 32; o > 0; o >>= 1) v = fmaxf(v, __shfl_down(v, o));
  return v;
}
__device__ inline float waveMin(float v) {
#pragma unroll
  for (int o = 32; o > 0; o >>= 1) v = fminf(v, __shfl_down(v, o));
  return v;
}
__device__ inline float smooth_l1(float d) {
  d = fabsf(d);
  return d < 0.1f ? 5.0f * d * d : d - 0.05f;
}

// Grid: [0,64) chamfer+sep | [64,128) cov | [128,192) reg | 192 joint
//       [193,705) surf: s=bid-193, b=s>>4, chunk c=s&15 (512 pts);
//                 wave owns 128-pt slice, lane owns 8 nodes (lane+64q)
__global__ __launch_bounds__(256) void mega_kernel(
    const float* __restrict__ coefs,
    const float* __restrict__ preds,
    const float* __restrict__ nodes,
    const float* __restrict__ cloud,
    const int* __restrict__ cls,
    const float* __restrict__ pjl, const float* __restrict__ pja,
    const float* __restrict__ gjl, const float* __restrict__ gja,
    const float* __restrict__ gps,
    float* __restrict__ ws) {
  const int bid = blockIdx.x;
  const int t = threadIdx.x;
  const int wave = t >> 6, lane = t & 63;
  __shared__ float4 sh4[512];     // 8 KB
  __shared__ float shg[2048];     // 8 KB (cross-wave combine)
  __shared__ float red[12][4];

  if (bid < 64) {
    // ---------------- chamfer + separation per (b,k) ----------------
    const int bk = bid;
    const float* pb = preds + (size_t)bk * PP * 3;
    const float* nbp = nodes + (size_t)bk * PP * 3;
    {
      float x = pb[3 * t], y = pb[3 * t + 1], z = pb[3 * t + 2];
      sh4[t] = make_float4(x, y, z, x * x + y * y + z * z);         // preds
      x = nbp[3 * t]; y = nbp[3 * t + 1]; z = nbp[3 * t + 2];
      sh4[256 + t] = make_float4(x, y, z, x * x + y * y + z * z);   // nodes
    }
    __syncthreads();
    float4 ptv[4], ntv[4];
#pragma unroll
    for (int q = 0; q < 4; ++q) {
      ptv[q] = sh4[lane + q * 64];
      ntv[q] = sh4[256 + lane + q * 64];
    }
    const float s0 = gps[bk * 3 + 0], s1 = gps[bk * 3 + 1], s2 = gps[bk * 3 + 2];
    const float thr = sqrtf(s0 * s0 + s1 * s1 + s2 * s2) * 0.125f;
    float g1[4], g2[4], sep = 0.0f;
#pragma unroll
    for (int q = 0; q < 4; ++q) { g1[q] = 1e30f; g2[q] = 1e30f; }
    const int j0 = wave * 64;
#pragma unroll 2
    for (int jj = 0; jj < 64; ++jj) {
      const int j = j0 + jj;
      const float4 pj = sh4[j];
      const float4 nj = sh4[256 + j];
#pragma unroll
      for (int q = 0; q < 4; ++q) {
        float dot = fmaf(ptv[q].x, nj.x, fmaf(ptv[q].y, nj.y, ptv[q].z * nj.z));
        g1[q] = fminf(g1[q], fmaf(-2.0f, dot, nj.w));
        dot = fmaf(ntv[q].x, pj.x, fmaf(ntv[q].y, pj.y, ntv[q].z * pj.z));
        g2[q] = fminf(g2[q], fmaf(-2.0f, dot, pj.w));
        dot = fmaf(ntv[q].x, nj.x, fmaf(ntv[q].y, nj.y, ntv[q].z * nj.z));
        const float d2 = fmaf(-2.0f, dot, ntv[q].w + nj.w);
        const float d = sqrtf(fmaxf(d2, 0.0f));
        if (j != lane + q * 64) sep += fmaxf(thr - d, 0.0f);
      }
    }
#pragma unroll
    for (int q = 0; q < 4; ++q) {
      shg[wave * 256 + lane + q * 64] = g1[q];
      shg[1024 + wave * 256 + lane + q * 64] = g2[q];
    }
    __syncthreads();
    const float gf = fminf(fminf(shg[t], shg[256 + t]),
                           fminf(shg[512 + t], shg[768 + t]));
    const float gb = fminf(fminf(shg[1024 + t], shg[1280 + t]),
                           fminf(shg[1536 + t], shg[1792 + t]));
    float chf = sqrtf(fmaxf(sh4[t].w + gf, 1e-12f)) +
                sqrtf(fmaxf(sh4[256 + t].w + gb, 1e-12f));
    chf = waveSum(chf);
    sep = waveSum(sep);
    if (lane == 0) { red[0][wave] = chf; red[1][wave] = sep; }
    __syncthreads();
    if (t == 0) {
      ws[SL_CHF + bid] = red[0][0] + red[0][1] + red[0][2] + red[0][3];
      ws[SL_SEP + bid] = red[1][0] + red[1][1] + red[1][2] + red[1][3];
    }

  } else if (bid < 128) {
    // ---------------- coverage per (b,k) ----------------
    const int bk = bid - 64;
    const int b = bk >> 1;
    const int k = bk & 1;
    float pmax0 = -1e9f, pmax1 = -1e9f, pmax2 = -1e9f;
    float pmin0 = 1e9f, pmin1 = 1e9f, pmin2 = 1e9f;
    const float* cb = cloud + (size_t)b * NCLOUD * 3;
    const int* lb = cls + (size_t)b * NCLOUD;
    for (int i = t; i < NCLOUD; i += 256) {
      if (lb[i] == k) {
        const float x = cb[i * 3 + 0], y = cb[i * 3 + 1], z = cb[i * 3 + 2];
        pmax0 = fmaxf(pmax0, x); pmax1 = fmaxf(pmax1, y); pmax2 = fmaxf(pmax2, z);
        pmin0 = fminf(pmin0, x); pmin1 = fminf(pmin1, y); pmin2 = fminf(pmin2, z);
      }
    }
    const float* nb = nodes + (size_t)bk * PP * 3;
    const float kx = nb[t * 3 + 0], ky = nb[t * 3 + 1], kz = nb[t * 3 + 2];
    pmax0 = waveMax(pmax0); pmax1 = waveMax(pmax1); pmax2 = waveMax(pmax2);
    pmin0 = waveMin(pmin0); pmin1 = waveMin(pmin1); pmin2 = waveMin(pmin2);
    float kmax0 = waveMax(kx), kmax1 = waveMax(ky), kmax2 = waveMax(kz);
    float kmin0 = waveMin(kx), kmin1 = waveMin(ky), kmin2 = waveMin(kz);
    if (lane == 0) {
      red[0][wave] = pmax0; red[1][wave] = pmax1; red[2][wave] = pmax2;
      red[3][wave] = pmin0; red[4][wave] = pmin1; red[5][wave] = pmin2;
      red[6][wave] = kmax0; red[7][wave] = kmax1; red[8][wave] = kmax2;
      red[9][wave] = kmin0; red[10][wave] = kmin1; red[11][wave] = kmin2;
    }
    __syncthreads();
    if (t == 0) {
      float v[12];
#pragma unroll
      for (int q = 0; q < 12; ++q) {
        if (q < 3 || (q >= 6 && q < 9))
          v[q] = fmaxf(fmaxf(red[q][0], red[q][1]), fmaxf(red[q][2], red[q][3]));
        else
          v[q] = fminf(fminf(red[q][0], red[q][1]), fminf(red[q][2], red[q][3]));
      }
      float s = 0.0f;
#pragma unroll
      for (int c2 = 0; c2 < 3; ++c2)
        s += 0.5f * (smooth_l1(v[6 + c2] - v[0 + c2]) + smooth_l1(v[9 + c2] - v[3 + c2]));
      ws[SL_COV + bk] = s;
    }

  } else if (bid < 192) {
    // ---------------- regularizer ----------------
    const int r = bid - 128;
    const float4* c4 = (const float4*)coefs;
    float v = 0.0f;
    for (int i = r * 256 + t; i < NCOEF / 4; i += 64 * 256) {
      const float4 q = c4[i];
      v += q.x * q.x + q.y * q.y + q.z * q.z + q.w * q.w;
    }
    v = waveSum(v);
    if (lane == 0) red[0][wave] = v;
    __syncthreads();
    if (t == 0)
      ws[SL_REG + r] = red[0][0] + red[0][1] + red[0][2] + red[0][3];

  } else if (bid == 192) {
    // ---------------- joint ----------------
    float cosv = 0.0f, locv = 0.0f;
    if (t < NB) {
      const float axj = pja[t * 3 + 0], ayj = pja[t * 3 + 1], azj = pja[t * 3 + 2];
      const float gx = gja[t * 3 + 0], gy = gja[t * 3 + 1], gz = gja[t * 3 + 2];
      const float dot = axj * gx + ayj * gy + azj * gz;
      const float na = sqrtf(axj * axj + ayj * ayj + azj * azj);
      const float nbn = sqrtf(gx * gx + gy * gy + gz * gz);
      cosv = dot / fmaxf(na * nbn, 1e-8f);
      const float ux = gx / nbn, uy = gy / nbn, uz = gz / nbn;
      const float px = gjl[t * 3 + 0], py = gjl[t * 3 + 1], pz = gjl[t * 3 + 2];
      const float qx = px + ux, qy = py + uy, qz = pz + uz;
      const float rx = pjl[t * 3 + 0], ry = pjl[t * 3 + 1], rz = pjl[t * 3 + 2];
      const float xx = px - qx, xy = py - qy, xz = pz - qz;
      const float tnum = (rx - qx) * xx + (ry - qy) * xy + (rz - qz) * xz;
      const float tden = xx * xx + xy * xy + xz * xz;
      const float tv = tnum / tden;
      const float vx = tv * xx + (qx - rx);
      const float vy = tv * xy + (qy - ry);
      const float vz = tv * xz + (qz - rz);
      locv = sqrtf(vx * vx + vy * vy + vz * vz);
    }
    cosv = waveSum(cosv);
    locv = waveSum(locv);
    if (t == 0) { ws[SL_JNT + 0] = cosv; ws[SL_JNT + 1] = locv; }

  } else {
    // ---------------- surf partial: (b, 512-pt chunk) ----------------
    const int s = bid - SURF0;
    const int b = s >> 4;
    const int c = s & 15;
    const float* cb = cloud + ((size_t)b * NCLOUD + (size_t)c * 512) * 3;
#pragma unroll
    for (int g = 0; g < 2; ++g) {
      const int idx = g * 256 + t;
      const float qx = cb[3 * idx], qy = cb[3 * idx + 1], qz = cb[3 * idx + 2];
      sh4[idx] = make_float4(qx, qy, qz, 0.5f * (qx * qx + qy * qy + qz * qz));
    }
    __syncthreads();
    const float* nb = nodes + (size_t)b * NNODES * 3;
    float nxv[8], nyv[8], nzv[8], mg[8];
#pragma unroll
    for (int q = 0; q < 8; ++q) {
      const int n = lane + q * 64;
      nxv[q] = nb[3 * n]; nyv[q] = nb[3 * n + 1]; nzv[q] = nb[3 * n + 2];
      mg[q] = 1e30f;
    }
    const int p0 = wave * 128;
#pragma unroll 4
    for (int j = 0; j < 128; ++j) {
      const float4 q4 = sh4[p0 + j];
#pragma unroll
      for (int q = 0; q < 8; ++q)
        mg[q] = fminf(mg[q],
                      fmaf(-nxv[q], q4.x,
                           fmaf(-nyv[q], q4.y, fmaf(-nzv[q], q4.z, q4.w))));
    }
    // cross-wave min combine in LDS, then coalesced store of min-g (no nn)
#pragma unroll
    for (int q = 0; q < 8; ++q)
      shg[wave * 512 + lane + q * 64] = mg[q];
    __syncthreads();
    float* pout = ws + PART0 + ((size_t)b * NCHUNK + c) * NNODES;
#pragma unroll
    for (int g = 0; g < 2; ++g) {
      const int node = g * 256 + t;
      pout[node] = fminf(fminf(shg[node], shg[512 + node]),
                         fminf(shg[1024 + node], shg[1536 + node]));
    }
  }
}

// ---------------- final1: per-batch min-g over chunks -> sqrt-sum ----------------
__global__ __launch_bounds__(256) void final1_kernel(
    const float* __restrict__ nodes, float* __restrict__ ws) {
  const int b = blockIdx.x;
  const int t = threadIdx.x;
  const float* partial = ws + PART0;
  const float* nb = nodes + (size_t)b * NNODES * 3;
  float ssum = 0.0f;
#pragma unroll
  for (int g = 0; g < 2; ++g) {
    const int node = g * 256 + t;
    float m = 1e30f;
#pragma unroll
    for (int c = 0; c < NCHUNK; ++c)
      m = fminf(m, partial[((size_t)b * NCHUNK + c) * NNODES + node]);
    const float x = nb[3 * node], y = nb[3 * node + 1], z = nb[3 * node + 2];
    const float nn = x * x + y * y + z * z;
    ssum += sqrtf(fmaxf(fmaf(2.0f, m, nn), 1e-12f));
  }
  ssum = waveSum(ssum);
  __shared__ float r[4];
  const int wave = t >> 6, lane = t & 63;
  if (lane == 0) r[wave] = ssum;
  __syncthreads();
  if (t == 0) ws[SL_SB + b] = r[0] + r[1] + r[2] + r[3];
}

// ---------------- final2: one wave sums all slots ----------------
__global__ __launch_bounds__(64) void final2_kernel(
    const float* __restrict__ ws, float* __restrict__ out) {
  const int t = threadIdx.x;
  float chf_s = ws[SL_CHF + t];
  float sep_s = ws[SL_SEP + t];
  float cov_s = ws[SL_COV + t];
  float reg_s = ws[SL_REG + t];
  float srf_s = (t < NB) ? ws[SL_SB + t] : 0.0f;
  chf_s = waveSum(chf_s);
  sep_s = waveSum(sep_s);
  cov_s = waveSum(cov_s);
  reg_s = waveSum(reg_s);
  srf_s = waveSum(srf_s);
  if (t == 0) {
    const float chf = chf_s / (float)(KK * NB * PP);
    const float sep = sep_s / (float)(NB * KK * PP * (PP - 1));
    const float surf = srf_s / (float)(NB * NNODES);
    const float cov = cov_s / (float)(NB * KK * 3);
    const float axis = 1.0f - ws[SL_JNT + 0] / (float)NB;
    const float loc = ws[SL_JNT + 1] / (float)NB;
    const float reg = reg_s / (float)NCOEF;
    out[0] = chf + cov + surf * 5.0f + (loc + 0.5f * axis) + reg * 0.01f + sep * 2.0f;
  }
}

extern "C" void kernel_launch(void* const* d_in, const int* in_sizes, int n_in,
                              void* d_out, int out_size, void* d_ws, size_t ws_size,
                              hipStream_t stream) {
  const float* coefs = (const float*)d_in[0];
  const float* preds = (const float*)d_in[1];
  const float* nodes = (const float*)d_in[2];
  const float* cloud = (const float*)d_in[3];
  const int* cls = (const int*)d_in[4];
  const float* pjl = (const float*)d_in[5];
  const float* pja = (const float*)d_in[6];
  const float* gjl = (const float*)d_in[7];
  const float* gja = (const float*)d_in[8];
  const float* gps = (const float*)d_in[9];
  float* out = (float*)d_out;
  float* ws = (float*)d_ws;

  mega_kernel<<<NBLK, 256, 0, stream>>>(coefs, preds, nodes, cloud, cls,
                                        pjl, pja, gjl, gja, gps, ws);
  final1_kernel<<<NB, 256, 0, stream>>>(nodes, ws);
  final2_kernel<<<1, 64, 0, stream>>>(ws, out);
}